// Round 1
// baseline (319.987 us; speedup 1.0000x reference)
//
#include <hip/hip_runtime.h>

#define XD 256
#define NI 128
#define ND 384
#define BATCH 256
#define NSTEPS 5
#define NS_ITERS 7

// workspace float offsets
#define K_OFF   0
#define X0_OFF  (65536)
#define X1_OFF  (65536*2)
#define T_OFF   (65536*3)
#define U_OFF   (65536*4)                 // 384*384 = 147456
#define ZA_OFF  (65536*4 + 147456)        // 409600
#define ZB_OFF  (ZA_OFF + BATCH*ND)      // 507904
#define W_OFF   (ZB_OFF + BATCH*ND)      // 606208
#define SC_OFF  (W_OFF + BATCH*ND)       // 704512

// ---------------------------------------------------------------------------
// Generic 32x32-tile f32 GEMM: C[M,N] = scale * (A @ B or A @ B^T) + caddScale*Cadd
// block(16,16), each thread 2x2. All dims multiples of 32 in our uses.
// ---------------------------------------------------------------------------
template<bool BT>
__global__ __launch_bounds__(256)
void gemm_kernel(const float* __restrict__ A, int lda,
                 const float* __restrict__ B, int ldb,
                 float* __restrict__ C, int ldc,
                 int M, int N, int K, float scale,
                 const float* __restrict__ Cadd, int ldca, float caddScale)
{
    __shared__ float As[32][33];
    __shared__ float Bs[32][33];
    const int tx = threadIdx.x, ty = threadIdx.y;
    const int tid = ty * 16 + tx;
    const int n0 = blockIdx.x * 32, m0 = blockIdx.y * 32;
    float acc00 = 0.f, acc01 = 0.f, acc10 = 0.f, acc11 = 0.f;

    for (int k0 = 0; k0 < K; k0 += 32) {
#pragma unroll
        for (int it = 0; it < 4; ++it) {
            int idx = tid + it * 256;
            int mm = idx >> 5, kk = idx & 31;
            As[mm][kk] = A[(m0 + mm) * lda + (k0 + kk)];
        }
#pragma unroll
        for (int it = 0; it < 4; ++it) {
            int idx = tid + it * 256;
            if (BT) {
                int nn = idx >> 5, kk = idx & 31;
                Bs[kk][nn] = B[(n0 + nn) * ldb + (k0 + kk)];
            } else {
                int kk = idx >> 5, nn = idx & 31;
                Bs[kk][nn] = B[(k0 + kk) * ldb + (n0 + nn)];
            }
        }
        __syncthreads();
#pragma unroll
        for (int kk = 0; kk < 32; ++kk) {
            float a0 = As[2 * ty][kk], a1 = As[2 * ty + 1][kk];
            float b0 = Bs[kk][2 * tx], b1 = Bs[kk][2 * tx + 1];
            acc00 += a0 * b0; acc01 += a0 * b1;
            acc10 += a1 * b0; acc11 += a1 * b1;
        }
        __syncthreads();
    }

    float accs[2][2] = {{acc00, acc01}, {acc10, acc11}};
#pragma unroll
    for (int i = 0; i < 2; ++i)
#pragma unroll
        for (int j = 0; j < 2; ++j) {
            int m = m0 + 2 * ty + i, n = n0 + 2 * tx + j;
            float v = scale * accs[i][j];
            if (Cadd) v += caddScale * Cadd[m * ldca + n];
            C[m * ldc + n] = v;
        }
}

// ---------------------------------------------------------------------------
// K = A^T A + Q + I   (256x256, inner K = NI = 128)
// ---------------------------------------------------------------------------
__global__ __launch_bounds__(256)
void build_K_kernel(const float* __restrict__ A, const float* __restrict__ Q,
                    float* __restrict__ Kout)
{
    __shared__ float Ai[32][33];
    __shared__ float Aj[32][33];
    const int tx = threadIdx.x, ty = threadIdx.y;
    const int tid = ty * 16 + tx;
    const int n0 = blockIdx.x * 32, m0 = blockIdx.y * 32;
    float acc00 = 0.f, acc01 = 0.f, acc10 = 0.f, acc11 = 0.f;

    for (int k0 = 0; k0 < NI; k0 += 32) {
#pragma unroll
        for (int it = 0; it < 4; ++it) {
            int idx = tid + it * 256;
            int kk = idx >> 5, col = idx & 31;
            Ai[kk][col] = A[(k0 + kk) * XD + (m0 + col)];
            Aj[kk][col] = A[(k0 + kk) * XD + (n0 + col)];
        }
        __syncthreads();
#pragma unroll
        for (int kk = 0; kk < 32; ++kk) {
            float a0 = Ai[kk][2 * ty], a1 = Ai[kk][2 * ty + 1];
            float b0 = Aj[kk][2 * tx], b1 = Aj[kk][2 * tx + 1];
            acc00 += a0 * b0; acc01 += a0 * b1;
            acc10 += a1 * b0; acc11 += a1 * b1;
        }
        __syncthreads();
    }

    float accs[2][2] = {{acc00, acc01}, {acc10, acc11}};
#pragma unroll
    for (int i = 0; i < 2; ++i)
#pragma unroll
        for (int j = 0; j < 2; ++j) {
            int m = m0 + 2 * ty + i, n = n0 + 2 * tx + j;
            float v = accs[i][j] + Q[m * XD + n];
            if (m == n) v += 1.0f;
            Kout[m * XD + n] = v;
        }
}

// ---------------------------------------------------------------------------
// Gershgorin bound via column abs-sums (K symmetric), then c = 2/(2+R)
// ---------------------------------------------------------------------------
__global__ __launch_bounds__(256)
void rowmax_kernel(const float* __restrict__ K, float* __restrict__ sc)
{
    const int t = threadIdx.x;
    float s = 0.f;
    for (int j = 0; j < XD; ++j) s += fabsf(K[j * XD + t]);
    __shared__ float red[256];
    red[t] = s;
    __syncthreads();
    for (int off = 128; off; off >>= 1) {
        if (t < off) red[t] = fmaxf(red[t], red[t + off]);
        __syncthreads();
    }
    if (t == 0) sc[0] = 2.0f / (2.0f + red[0]);
}

// X0 = 2c I - c^2 K   (fused first Newton-Schulz step from X=cI)
__global__ __launch_bounds__(256)
void ns_init_kernel(const float* __restrict__ K, const float* __restrict__ sc,
                    float* __restrict__ X)
{
    int idx = blockIdx.x * 256 + threadIdx.x;
    float c = sc[0];
    int i = idx >> 8, j = idx & 255;
    float v = -c * c * K[idx];
    if (i == j) v += 2.0f * c;
    X[idx] = v;
}

// copy X (K^-1) into U top-left block
__global__ __launch_bounds__(256)
void copyXU_kernel(const float* __restrict__ X, float* __restrict__ U)
{
    int idx = blockIdx.x * 256 + threadIdx.x;
    int i = idx >> 8, j = idx & 255;
    U[i * ND + j] = X[idx];
}

// z = [x, 0], w = 0, xhist[0] = z
__global__ __launch_bounds__(256)
void init_state_kernel(const float* __restrict__ x, float* __restrict__ z,
                       float* __restrict__ w, float* __restrict__ xh0)
{
    int idx = blockIdx.x * 256 + threadIdx.x;   // over BATCH*ND
    int b = idx / ND, i = idx % ND;
    float v = (i < XD) ? x[b * XD + i] : 0.0f;
    z[idx] = v;
    w[idx] = 0.0f;
    xh0[idx] = v;
}

// ---------------------------------------------------------------------------
// One ADMM step: xk = (z-p) @ U^T + [0; p_s], then clip / dual update.
// zin read-only (GEMM operand), zout separate buffer (avoid inter-block race).
// w updated in place (only read at own (m,n)).
// ---------------------------------------------------------------------------
template<bool LAST>
__global__ __launch_bounds__(256)
void step_kernel(const float* __restrict__ zin, float* __restrict__ zout,
                 float* __restrict__ w, const float* __restrict__ p,
                 const float* __restrict__ U,
                 float* __restrict__ xhist,
                 float* __restrict__ xout, float* __restrict__ rgap,
                 float* __restrict__ sgap)
{
    __shared__ float Es[32][33];
    __shared__ float Us[32][33];
    const int tx = threadIdx.x, ty = threadIdx.y;
    const int tid = ty * 16 + tx;
    const int n0 = blockIdx.x * 32, m0 = blockIdx.y * 32;
    float acc00 = 0.f, acc01 = 0.f, acc10 = 0.f, acc11 = 0.f;

    for (int k0 = 0; k0 < ND; k0 += 32) {
#pragma unroll
        for (int it = 0; it < 4; ++it) {
            int idx = tid + it * 256;
            int mm = idx >> 5, kk = idx & 31;
            int g = (m0 + mm) * ND + (k0 + kk);
            Es[mm][kk] = zin[g] - p[g];
        }
#pragma unroll
        for (int it = 0; it < 4; ++it) {
            int idx = tid + it * 256;
            int nn = idx >> 5, kk = idx & 31;
            Us[kk][nn] = U[(n0 + nn) * ND + (k0 + kk)];
        }
        __syncthreads();
#pragma unroll
        for (int kk = 0; kk < 32; ++kk) {
            float a0 = Es[2 * ty][kk], a1 = Es[2 * ty + 1][kk];
            float b0 = Us[kk][2 * tx], b1 = Us[kk][2 * tx + 1];
            acc00 += a0 * b0; acc01 += a0 * b1;
            acc10 += a1 * b0; acc11 += a1 * b1;
        }
        __syncthreads();
    }

    float accs[2][2] = {{acc00, acc01}, {acc10, acc11}};
#pragma unroll
    for (int i = 0; i < 2; ++i)
#pragma unroll
        for (int j = 0; j < 2; ++j) {
            int m = m0 + 2 * ty + i, n = n0 + 2 * tx + j;
            int g = m * ND + n;
            float xk = accs[i][j] + ((n >= XD) ? p[g] : 0.0f);
            float zv = zin[g];
            float wv = w[g];
            float v = xk + wv;
            float lo = (n < XD) ? -1000.0f : 0.0f;
            float ynew = fminf(fmaxf(v, lo), 1000.0f);
            float wnew = v - ynew;
            xhist[g] = xk;
            zout[g] = 2.0f * ynew - v;
            w[g] = wnew;
            if (LAST) {
                rgap[g] = xk - ynew;
                sgap[g] = ynew - (zv + wv);
                if (n < XD) xout[m * XD + n] = xk;
            }
        }
}

// ---------------------------------------------------------------------------
extern "C" void kernel_launch(void* const* d_in, const int* in_sizes, int n_in,
                              void* d_out, int out_size, void* d_ws, size_t ws_size,
                              hipStream_t stream)
{
    const float* x = (const float*)d_in[0];
    const float* p = (const float*)d_in[1];
    const float* Q = (const float*)d_in[2];
    const float* A = (const float*)d_in[3];

    float* ws = (float*)d_ws;
    float* Kw   = ws + K_OFF;
    float* Xbuf[2] = { ws + X0_OFF, ws + X1_OFF };
    float* T    = ws + T_OFF;
    float* U    = ws + U_OFF;
    float* Z[2] = { ws + ZA_OFF, ws + ZB_OFF };
    float* W    = ws + W_OFF;
    float* sc   = ws + SC_OFF;

    float* out   = (float*)d_out;
    float* xout  = out;                        // (B, XD)
    float* rgap  = out + BATCH * XD;           // (B, ND)
    float* sgap  = rgap + BATCH * ND;          // (B, ND)
    float* xhist = sgap + BATCH * ND;          // (STEPS+1, B, ND)

    dim3 blk(16, 16);

    // K = A^T A + Q + I
    build_K_kernel<<<dim3(8, 8), blk, 0, stream>>>(A, Q, Kw);
    // Gershgorin -> c
    rowmax_kernel<<<1, 256, 0, stream>>>(Kw, sc);
    // X0 = 2cI - c^2 K
    ns_init_kernel<<<256, 256, 0, stream>>>(Kw, sc, Xbuf[0]);

    // Newton-Schulz: X <- 2X - X K X
    int cur = 0;
    for (int it = 0; it < NS_ITERS; ++it) {
        gemm_kernel<false><<<dim3(8, 8), blk, 0, stream>>>(
            Kw, XD, Xbuf[cur], XD, T, XD, XD, XD, XD, 1.0f, nullptr, 0, 0.0f);
        gemm_kernel<false><<<dim3(8, 8), blk, 0, stream>>>(
            Xbuf[cur], XD, T, XD, Xbuf[cur ^ 1], XD, XD, XD, XD, -1.0f,
            Xbuf[cur], XD, 2.0f);
        cur ^= 1;
    }

    // U assembly: U = [[Kinv, -Kinv A^T], [-A Kinv, A Kinv A^T]]
    copyXU_kernel<<<256, 256, 0, stream>>>(Xbuf[cur], U);
    // U top-right = -X @ A^T   (M=XD, N=NI, K=XD)
    gemm_kernel<true><<<dim3(4, 8), blk, 0, stream>>>(
        Xbuf[cur], XD, A, XD, U + XD, ND, XD, NI, XD, -1.0f, nullptr, 0, 0.0f);
    // U bottom = -A @ U_top    (M=NI, N=ND, K=XD)
    gemm_kernel<false><<<dim3(12, 4), blk, 0, stream>>>(
        A, XD, U, ND, U + XD * ND, ND, NI, ND, XD, -1.0f, nullptr, 0, 0.0f);

    // state init
    init_state_kernel<<<384, 256, 0, stream>>>(x, Z[0], W, xhist);

    // 5 ADMM steps
    for (int s = 0; s < NSTEPS; ++s) {
        float* zin = Z[s & 1];
        float* zout_ = Z[(s & 1) ^ 1];
        float* xh = xhist + (size_t)(s + 1) * BATCH * ND;
        if (s == NSTEPS - 1)
            step_kernel<true><<<dim3(12, 8), blk, 0, stream>>>(
                zin, zout_, W, p, U, xh, xout, rgap, sgap);
        else
            step_kernel<false><<<dim3(12, 8), blk, 0, stream>>>(
                zin, zout_, W, p, U, xh, xout, rgap, sgap);
    }
}